// Round 1
// baseline (5817.152 us; speedup 1.0000x reference)
//
#include <hip/hip_runtime.h>

#define N_NODES 50000
#define N_EDGES 800000
#define DIM 128

// ---------------------------------------------------------------------------
// 1) degree histogram: cnt[idx[e]] += 1
// ---------------------------------------------------------------------------
__global__ __launch_bounds__(256) void count_deg(const int* __restrict__ idx,
                                                 int* __restrict__ cnt, int E) {
    int i = blockIdx.x * blockDim.x + threadIdx.x;
    if (i < E) atomicAdd(&cnt[idx[i]], 1);
}

// 2) in-place: int count -> float rsqrt(max(count,1))
__global__ __launch_bounds__(256) void deg_to_rinv(int* __restrict__ buf, int n) {
    int i = blockIdx.x * blockDim.x + threadIdx.x;
    if (i < n) {
        int c = buf[i];
        float v = rsqrtf((float)(c < 1 ? 1 : c));
        ((float*)buf)[i] = v;
    }
}

// ---------------------------------------------------------------------------
// 3) edge scatter: agg[dst[e]] += x[src[e]] * rinv_src[src[e]]
//    32 lanes per edge, float4 per lane (512B per edge row).
// ---------------------------------------------------------------------------
__global__ __launch_bounds__(256) void scatter_edges(
    const float* __restrict__ x, const float* __restrict__ rinv_src,
    const int* __restrict__ src, const int* __restrict__ dst,
    float* agg, int E)
{
    int lane = threadIdx.x & 31;
    int e = blockIdx.x * 8 + (threadIdx.x >> 5);
    if (e >= E) return;
    int s = src[e];
    int d = dst[e];
    float sc = rinv_src[s];
    float4 v = ((const float4*)x)[(size_t)s * (DIM / 4) + lane];
    float* o = agg + (size_t)d * DIM + lane * 4;
    unsafeAtomicAdd(o + 0, v.x * sc);
    unsafeAtomicAdd(o + 1, v.y * sc);
    unsafeAtomicAdd(o + 2, v.z * sc);
    unsafeAtomicAdd(o + 3, v.w * sc);
}

// ---------------------------------------------------------------------------
// 4) row-scaled GEMM (+optional second input summed in):
//    out = (aggA * rinvA[:,None]) @ WA + bA  [+ (aggB * rinvB[:,None]) @ WB + bB]
//    Writes result to outA (and outB if non-null). out may alias agg (in-place
//    safe: each block stages its own rows into LDS before writing).
//    Block: 256 threads, 32 rows of 128 cols. Thread (rg=tid>>5, cg=tid&31)
//    computes rows {rg, rg+8, rg+16, rg+24} x cols [cg*4, cg*4+4).
// ---------------------------------------------------------------------------
__global__ __launch_bounds__(256) void gemm_pair(
    const float* aggA, const float* __restrict__ rinvA,
    const float* __restrict__ WA, const float* __restrict__ bA,
    const float* aggB, const float* __restrict__ rinvB,
    const float* __restrict__ WB, const float* __restrict__ bB,
    float* outA, float* outB, int n)
{
    __shared__ float Ws[128 * 128];      // 64 KiB
    __shared__ float xs[32 * 128];       // 16 KiB
    const int tid = threadIdx.x;
    const int row0 = blockIdx.x * 32;
    const int cg = tid & 31;
    const int rg = tid >> 5;
    const int c0 = cg * 4;

    float acc[4][4];
#pragma unroll
    for (int r = 0; r < 4; r++)
#pragma unroll
        for (int j = 0; j < 4; j++) acc[r][j] = 0.f;

    for (int pass = 0; pass < 2; ++pass) {
        const float* agg  = pass ? aggB  : aggA;
        const float* rinv = pass ? rinvB : rinvA;
        const float* W    = pass ? WB    : WA;
        const float* b    = pass ? bB    : bA;
        if (agg == nullptr) break;
        if (pass) __syncthreads();   // protect LDS reuse across passes

        // stage W: 4096 float4, 16 per thread
#pragma unroll
        for (int i = 0; i < 16; i++) {
            int f4 = tid + i * 256;
            ((float4*)Ws)[f4] = ((const float4*)W)[f4];
        }
        // stage 32 scaled rows: 1024 float4, 4 per thread
#pragma unroll
        for (int i = 0; i < 4; i++) {
            int f4 = tid + i * 256;          // 0..1023
            int r = f4 >> 5;                 // row in tile
            int row = row0 + r;
            float4 v = make_float4(0.f, 0.f, 0.f, 0.f);
            float s = 0.f;
            if (row < n) {
                v = ((const float4*)agg)[(size_t)row * 32 + (f4 & 31)];
                s = rinv[row];
            }
            ((float4*)xs)[f4] = make_float4(v.x * s, v.y * s, v.z * s, v.w * s);
        }
        __syncthreads();

        // bias (added once per pass to every row's accumulator)
        float4 bb = ((const float4*)b)[cg];
#pragma unroll
        for (int r = 0; r < 4; r++) {
            acc[r][0] += bb.x; acc[r][1] += bb.y; acc[r][2] += bb.z; acc[r][3] += bb.w;
        }

#pragma unroll 4
        for (int k = 0; k < 128; k++) {
            float4 w = ((const float4*)Ws)[k * 32 + cg];
            float x0 = xs[(rg)      * 128 + k];
            float x1 = xs[(rg + 8)  * 128 + k];
            float x2 = xs[(rg + 16) * 128 + k];
            float x3 = xs[(rg + 24) * 128 + k];
            acc[0][0] += x0 * w.x; acc[0][1] += x0 * w.y; acc[0][2] += x0 * w.z; acc[0][3] += x0 * w.w;
            acc[1][0] += x1 * w.x; acc[1][1] += x1 * w.y; acc[1][2] += x1 * w.z; acc[1][3] += x1 * w.w;
            acc[2][0] += x2 * w.x; acc[2][1] += x2 * w.y; acc[2][2] += x2 * w.z; acc[2][3] += x2 * w.w;
            acc[3][0] += x3 * w.x; acc[3][1] += x3 * w.y; acc[3][2] += x3 * w.z; acc[3][3] += x3 * w.w;
        }
    }

#pragma unroll
    for (int r = 0; r < 4; r++) {
        int row = row0 + rg + r * 8;
        if (row >= n) continue;
        float4 o = make_float4(acc[r][0], acc[r][1], acc[r][2], acc[r][3]);
        ((float4*)outA)[(size_t)row * 32 + cg] = o;
        if (outB) ((float4*)outB)[(size_t)row * 32 + cg] = o;
    }
}

// ---------------------------------------------------------------------------
extern "C" void kernel_launch(void* const* d_in, const int* in_sizes, int n_in,
                              void* d_out, int out_size, void* d_ws, size_t ws_size,
                              hipStream_t stream) {
    const float* feat_user_d1 = (const float*)d_in[0];
    const float* feat_user_d2 = (const float*)d_in[1];
    const float* feat_d1      = (const float*)d_in[2];
    const float* feat_d2      = (const float*)d_in[3];
    const float* W_i2u_d1 = (const float*)d_in[4];
    const float* b_i2u_d1 = (const float*)d_in[5];
    const float* W_i2u_d2 = (const float*)d_in[6];
    const float* b_i2u_d2 = (const float*)d_in[7];
    const float* W_u2i_d1 = (const float*)d_in[8];
    const float* b_u2i_d1 = (const float*)d_in[9];
    const float* W_u2i_d2 = (const float*)d_in[10];
    const float* b_u2i_d2 = (const float*)d_in[11];
    const int* src_i2u_d1 = (const int*)d_in[12];
    const int* dst_i2u_d1 = (const int*)d_in[13];
    const int* src_i2u_d2 = (const int*)d_in[14];
    const int* dst_i2u_d2 = (const int*)d_in[15];
    const int* src_u2i_d1 = (const int*)d_in[16];
    const int* dst_u2i_d1 = (const int*)d_in[17];
    const int* src_u2i_d2 = (const int*)d_in[18];
    const int* dst_u2i_d2 = (const int*)d_in[19];

    float* out = (float*)d_out;
    float* slot0 = out;                              // -> user (copy 1)
    float* slot1 = out + (size_t)N_NODES * DIM;      // -> user (copy 2)
    float* slot2 = out + 2 * (size_t)N_NODES * DIM;  // -> out_d1
    float* slot3 = out + 3 * (size_t)N_NODES * DIM;  // -> out_d2

    // ws: 8 degree/rinv arrays of N_NODES (int then float in place)
    int* deg = (int*)d_ws;
    const float* rinv = (const float*)d_ws;

    hipMemsetAsync(deg, 0, 8 * (size_t)N_NODES * sizeof(int), stream);
    hipMemsetAsync(d_out, 0, (size_t)out_size * sizeof(float), stream);

    int db = (N_EDGES + 255) / 256;
    // slot order: [r*2] = src-degree, [r*2+1] = dst-degree for
    // r in {i2u_d1, i2u_d2, u2i_d1, u2i_d2}
    count_deg<<<db, 256, 0, stream>>>(src_i2u_d1, deg + 0 * N_NODES, N_EDGES);
    count_deg<<<db, 256, 0, stream>>>(dst_i2u_d1, deg + 1 * N_NODES, N_EDGES);
    count_deg<<<db, 256, 0, stream>>>(src_i2u_d2, deg + 2 * N_NODES, N_EDGES);
    count_deg<<<db, 256, 0, stream>>>(dst_i2u_d2, deg + 3 * N_NODES, N_EDGES);
    count_deg<<<db, 256, 0, stream>>>(src_u2i_d1, deg + 4 * N_NODES, N_EDGES);
    count_deg<<<db, 256, 0, stream>>>(dst_u2i_d1, deg + 5 * N_NODES, N_EDGES);
    count_deg<<<db, 256, 0, stream>>>(src_u2i_d2, deg + 6 * N_NODES, N_EDGES);
    count_deg<<<db, 256, 0, stream>>>(dst_u2i_d2, deg + 7 * N_NODES, N_EDGES);

    deg_to_rinv<<<(8 * N_NODES + 255) / 256, 256, 0, stream>>>(deg, 8 * N_NODES);

    // scatter: 8 edges per 256-thread block
    int sb = (N_EDGES + 7) / 8;
    scatter_edges<<<sb, 256, 0, stream>>>(feat_d1,      rinv + 0 * N_NODES, src_i2u_d1, dst_i2u_d1, slot0, N_EDGES);
    scatter_edges<<<sb, 256, 0, stream>>>(feat_d2,      rinv + 2 * N_NODES, src_i2u_d2, dst_i2u_d2, slot1, N_EDGES);
    scatter_edges<<<sb, 256, 0, stream>>>(feat_user_d1, rinv + 4 * N_NODES, src_u2i_d1, dst_u2i_d1, slot2, N_EDGES);
    scatter_edges<<<sb, 256, 0, stream>>>(feat_user_d2, rinv + 6 * N_NODES, src_u2i_d2, dst_u2i_d2, slot3, N_EDGES);

    int gb = (N_NODES + 31) / 32;
    // user = scaled(slot0)@W_i2u_d1 + b + scaled(slot1)@W_i2u_d2 + b, to slots 0 and 1
    gemm_pair<<<gb, 256, 0, stream>>>(slot0, rinv + 1 * N_NODES, W_i2u_d1, b_i2u_d1,
                                      slot1, rinv + 3 * N_NODES, W_i2u_d2, b_i2u_d2,
                                      slot0, slot1, N_NODES);
    // out_d1 (in place on slot2)
    gemm_pair<<<gb, 256, 0, stream>>>(slot2, rinv + 5 * N_NODES, W_u2i_d1, b_u2i_d1,
                                      nullptr, nullptr, nullptr, nullptr,
                                      slot2, nullptr, N_NODES);
    // out_d2 (in place on slot3)
    gemm_pair<<<gb, 256, 0, stream>>>(slot3, rinv + 7 * N_NODES, W_u2i_d2, b_u2i_d2,
                                      nullptr, nullptr, nullptr, nullptr,
                                      slot3, nullptr, N_NODES);
}

// Round 2
// 1048.479 us; speedup vs baseline: 5.5482x; 5.5482x over previous
//
#include <hip/hip_runtime.h>

#define N_NODES 50000
#define N_EDGES 800000
#define DIM 128

// ---------------------------------------------------------------------------
// 1) degree histogram: cnt[idx[e]] += 1
// ---------------------------------------------------------------------------
__global__ __launch_bounds__(256) void count_deg(const int* __restrict__ idx,
                                                 int* __restrict__ cnt, int E) {
    int i = blockIdx.x * blockDim.x + threadIdx.x;
    if (i < E) atomicAdd(&cnt[idx[i]], 1);
}

// 2) in-place: int count -> float rsqrt(max(count,1))
__global__ __launch_bounds__(256) void deg_to_rinv(int* __restrict__ buf, int n) {
    int i = blockIdx.x * blockDim.x + threadIdx.x;
    if (i < n) {
        int c = buf[i];
        float v = rsqrtf((float)(c < 1 ? 1 : c));
        ((float*)buf)[i] = v;
    }
}

// ---------------------------------------------------------------------------
// 3) exclusive scan of dst-degree -> CSR row offsets + cursor copy.
//    One block per relation (grid.x = 4), 256 threads, sequential chunks.
// ---------------------------------------------------------------------------
__global__ __launch_bounds__(256) void scan_offsets(const int* __restrict__ deg,
                                                    int* __restrict__ offs,
                                                    int* __restrict__ cursor) {
    const int r = blockIdx.x;
    const int* cnt = deg + (size_t)(2 * r + 1) * N_NODES;  // dst-degree slot
    int* off = offs + (size_t)r * (N_NODES + 1);
    int* cur = cursor + (size_t)r * N_NODES;

    __shared__ int sums[256];
    const int tid = threadIdx.x;
    const int CH = (N_NODES + 255) / 256;  // 196
    const int lo = tid * CH;
    const int hi = (lo + CH < N_NODES) ? lo + CH : N_NODES;

    int s = 0;
    for (int i = lo; i < hi; i++) s += cnt[i];
    sums[tid] = s;
    __syncthreads();
    // Hillis-Steele inclusive scan over 256 partial sums
    for (int d = 1; d < 256; d <<= 1) {
        int v = (tid >= d) ? sums[tid - d] : 0;
        __syncthreads();
        sums[tid] += v;
        __syncthreads();
    }
    int run = sums[tid] - s;  // exclusive prefix of this thread's chunk
    for (int i = lo; i < hi; i++) {
        off[i] = run;
        cur[i] = run;
        run += cnt[i];
    }
    if (tid == 255) off[N_NODES] = run;  // == E
}

// ---------------------------------------------------------------------------
// 4) CSR fill: csr[atomicAdd(cursor[dst[e]])] = src[e]
// ---------------------------------------------------------------------------
__global__ __launch_bounds__(256) void fill_csr(const int* __restrict__ src,
                                                const int* __restrict__ dst,
                                                int* __restrict__ cursor,
                                                int* __restrict__ csr, int E) {
    int e = blockIdx.x * blockDim.x + threadIdx.x;
    if (e < E) {
        int pos = atomicAdd(&cursor[dst[e]], 1);
        csr[pos] = src[e];
    }
}

// ---------------------------------------------------------------------------
// 5) gather: out[d] = rinv_dst[d] * sum_{s in csr[offs[d]:offs[d+1]]}
//                                        feat[s] * rinv_src[s]
//    One wave64 per dst node; lane holds float2 (128 = 64*2 cols).
// ---------------------------------------------------------------------------
__global__ __launch_bounds__(256) void gather_csr(
    const float* __restrict__ feat, const float* __restrict__ rinv_src,
    const int* __restrict__ csr, const int* __restrict__ offs,
    const float* __restrict__ rinv_dst, float* __restrict__ out, int n)
{
    const int node = blockIdx.x * 4 + (threadIdx.x >> 6);
    if (node >= n) return;
    const int lane = threadIdx.x & 63;
    const int beg = offs[node];
    const int end = offs[node + 1];

    float2 acc = make_float2(0.f, 0.f);
    int i = beg;
    // 2-way unroll for memory-level parallelism
    for (; i + 1 < end; i += 2) {
        int s0 = csr[i];
        int s1 = csr[i + 1];
        float sc0 = rinv_src[s0];
        float sc1 = rinv_src[s1];
        float2 v0 = ((const float2*)feat)[(size_t)s0 * 64 + lane];
        float2 v1 = ((const float2*)feat)[(size_t)s1 * 64 + lane];
        acc.x += v0.x * sc0 + v1.x * sc1;
        acc.y += v0.y * sc0 + v1.y * sc1;
    }
    if (i < end) {
        int s0 = csr[i];
        float sc0 = rinv_src[s0];
        float2 v0 = ((const float2*)feat)[(size_t)s0 * 64 + lane];
        acc.x += v0.x * sc0;
        acc.y += v0.y * sc0;
    }
    float rd = rinv_dst[node];
    ((float2*)out)[(size_t)node * 64 + lane] = make_float2(acc.x * rd, acc.y * rd);
}

// ---------------------------------------------------------------------------
// 6) GEMM (+optional second input summed in), agg already fully scaled:
//    out = aggA @ WA + bA  [+ aggB @ WB + bB]
//    In-place safe: each block stages its own 32 rows into LDS before writing.
// ---------------------------------------------------------------------------
__global__ __launch_bounds__(256) void gemm_pair(
    const float* aggA, const float* __restrict__ WA, const float* __restrict__ bA,
    const float* aggB, const float* __restrict__ WB, const float* __restrict__ bB,
    float* outA, float* outB, int n)
{
    __shared__ float Ws[128 * 128];      // 64 KiB
    __shared__ float xs[32 * 128];       // 16 KiB
    const int tid = threadIdx.x;
    const int row0 = blockIdx.x * 32;
    const int cg = tid & 31;
    const int rg = tid >> 5;

    float acc[4][4];
#pragma unroll
    for (int r = 0; r < 4; r++)
#pragma unroll
        for (int j = 0; j < 4; j++) acc[r][j] = 0.f;

    for (int pass = 0; pass < 2; ++pass) {
        const float* agg = pass ? aggB : aggA;
        const float* W   = pass ? WB   : WA;
        const float* b   = pass ? bB   : bA;
        if (agg == nullptr) break;
        if (pass) __syncthreads();

        // stage W: 4096 float4, 16 per thread
#pragma unroll
        for (int i = 0; i < 16; i++) {
            int f4 = tid + i * 256;
            ((float4*)Ws)[f4] = ((const float4*)W)[f4];
        }
        // stage 32 rows: 1024 float4, 4 per thread
#pragma unroll
        for (int i = 0; i < 4; i++) {
            int f4 = tid + i * 256;
            int r = f4 >> 5;
            int row = row0 + r;
            float4 v = make_float4(0.f, 0.f, 0.f, 0.f);
            if (row < n) v = ((const float4*)agg)[(size_t)row * 32 + (f4 & 31)];
            ((float4*)xs)[f4] = v;
        }
        __syncthreads();

        float4 bb = ((const float4*)b)[cg];
#pragma unroll
        for (int r = 0; r < 4; r++) {
            acc[r][0] += bb.x; acc[r][1] += bb.y; acc[r][2] += bb.z; acc[r][3] += bb.w;
        }

#pragma unroll 4
        for (int k = 0; k < 128; k++) {
            float4 w = ((const float4*)Ws)[k * 32 + cg];
            float x0 = xs[(rg)      * 128 + k];
            float x1 = xs[(rg + 8)  * 128 + k];
            float x2 = xs[(rg + 16) * 128 + k];
            float x3 = xs[(rg + 24) * 128 + k];
            acc[0][0] += x0 * w.x; acc[0][1] += x0 * w.y; acc[0][2] += x0 * w.z; acc[0][3] += x0 * w.w;
            acc[1][0] += x1 * w.x; acc[1][1] += x1 * w.y; acc[1][2] += x1 * w.z; acc[1][3] += x1 * w.w;
            acc[2][0] += x2 * w.x; acc[2][1] += x2 * w.y; acc[2][2] += x2 * w.z; acc[2][3] += x2 * w.w;
            acc[3][0] += x3 * w.x; acc[3][1] += x3 * w.y; acc[3][2] += x3 * w.z; acc[3][3] += x3 * w.w;
        }
    }

#pragma unroll
    for (int r = 0; r < 4; r++) {
        int row = row0 + rg + r * 8;
        if (row >= n) continue;
        float4 o = make_float4(acc[r][0], acc[r][1], acc[r][2], acc[r][3]);
        ((float4*)outA)[(size_t)row * 32 + cg] = o;
        if (outB) ((float4*)outB)[(size_t)row * 32 + cg] = o;
    }
}

// ---------------------------------------------------------------------------
extern "C" void kernel_launch(void* const* d_in, const int* in_sizes, int n_in,
                              void* d_out, int out_size, void* d_ws, size_t ws_size,
                              hipStream_t stream) {
    const float* feat_user_d1 = (const float*)d_in[0];
    const float* feat_user_d2 = (const float*)d_in[1];
    const float* feat_d1      = (const float*)d_in[2];
    const float* feat_d2      = (const float*)d_in[3];
    const float* W_i2u_d1 = (const float*)d_in[4];
    const float* b_i2u_d1 = (const float*)d_in[5];
    const float* W_i2u_d2 = (const float*)d_in[6];
    const float* b_i2u_d2 = (const float*)d_in[7];
    const float* W_u2i_d1 = (const float*)d_in[8];
    const float* b_u2i_d1 = (const float*)d_in[9];
    const float* W_u2i_d2 = (const float*)d_in[10];
    const float* b_u2i_d2 = (const float*)d_in[11];
    const int* src_i2u_d1 = (const int*)d_in[12];
    const int* dst_i2u_d1 = (const int*)d_in[13];
    const int* src_i2u_d2 = (const int*)d_in[14];
    const int* dst_i2u_d2 = (const int*)d_in[15];
    const int* src_u2i_d1 = (const int*)d_in[16];
    const int* dst_u2i_d1 = (const int*)d_in[17];
    const int* src_u2i_d2 = (const int*)d_in[18];
    const int* dst_u2i_d2 = (const int*)d_in[19];

    float* out = (float*)d_out;
    float* slot0 = out;                              // -> user (copy 1)
    float* slot1 = out + (size_t)N_NODES * DIM;      // -> user (copy 2)
    float* slot2 = out + 2 * (size_t)N_NODES * DIM;  // -> out_d1
    float* slot3 = out + 3 * (size_t)N_NODES * DIM;  // -> out_d2

    // ws layout:
    //   [0)                 deg/rinv : 8*N ints  (int counts -> float rinv in place)
    //   [8N)                offs     : 4*(N+1) ints
    //   [8N+4(N+1))         cursor   : 4*N ints
    //   [12N+4)             csr      : 4*E ints
    int* deg = (int*)d_ws;
    const float* rinv = (const float*)d_ws;
    int* offs   = deg + 8 * (size_t)N_NODES;
    int* cursor = offs + 4 * (size_t)(N_NODES + 1);
    int* csr    = cursor + 4 * (size_t)N_NODES;

    hipMemsetAsync(deg, 0, 8 * (size_t)N_NODES * sizeof(int), stream);

    int db = (N_EDGES + 255) / 256;
    // slot order: [r*2] = src-degree, [r*2+1] = dst-degree for
    // r in {i2u_d1, i2u_d2, u2i_d1, u2i_d2}
    count_deg<<<db, 256, 0, stream>>>(src_i2u_d1, deg + 0 * N_NODES, N_EDGES);
    count_deg<<<db, 256, 0, stream>>>(dst_i2u_d1, deg + 1 * N_NODES, N_EDGES);
    count_deg<<<db, 256, 0, stream>>>(src_i2u_d2, deg + 2 * N_NODES, N_EDGES);
    count_deg<<<db, 256, 0, stream>>>(dst_i2u_d2, deg + 3 * N_NODES, N_EDGES);
    count_deg<<<db, 256, 0, stream>>>(src_u2i_d1, deg + 4 * N_NODES, N_EDGES);
    count_deg<<<db, 256, 0, stream>>>(dst_u2i_d1, deg + 5 * N_NODES, N_EDGES);
    count_deg<<<db, 256, 0, stream>>>(src_u2i_d2, deg + 6 * N_NODES, N_EDGES);
    count_deg<<<db, 256, 0, stream>>>(dst_u2i_d2, deg + 7 * N_NODES, N_EDGES);

    // CSR offsets from dst-degrees (needs int counts; before deg_to_rinv)
    scan_offsets<<<4, 256, 0, stream>>>(deg, offs, cursor);

    deg_to_rinv<<<(8 * N_NODES + 255) / 256, 256, 0, stream>>>(deg, 8 * N_NODES);

    fill_csr<<<db, 256, 0, stream>>>(src_i2u_d1, dst_i2u_d1, cursor + 0 * N_NODES, csr + 0 * (size_t)N_EDGES, N_EDGES);
    fill_csr<<<db, 256, 0, stream>>>(src_i2u_d2, dst_i2u_d2, cursor + 1 * N_NODES, csr + 1 * (size_t)N_EDGES, N_EDGES);
    fill_csr<<<db, 256, 0, stream>>>(src_u2i_d1, dst_u2i_d1, cursor + 2 * N_NODES, csr + 2 * (size_t)N_EDGES, N_EDGES);
    fill_csr<<<db, 256, 0, stream>>>(src_u2i_d2, dst_u2i_d2, cursor + 3 * N_NODES, csr + 3 * (size_t)N_EDGES, N_EDGES);

    // gather: one wave64 per node, 4 nodes per block
    int gb2 = (N_NODES + 3) / 4;
    gather_csr<<<gb2, 256, 0, stream>>>(feat_d1, rinv + 0 * N_NODES,
                                        csr + 0 * (size_t)N_EDGES, offs + 0 * (N_NODES + 1),
                                        rinv + 1 * N_NODES, slot0, N_NODES);
    gather_csr<<<gb2, 256, 0, stream>>>(feat_d2, rinv + 2 * N_NODES,
                                        csr + 1 * (size_t)N_EDGES, offs + 1 * (N_NODES + 1),
                                        rinv + 3 * N_NODES, slot1, N_NODES);
    gather_csr<<<gb2, 256, 0, stream>>>(feat_user_d1, rinv + 4 * N_NODES,
                                        csr + 2 * (size_t)N_EDGES, offs + 2 * (N_NODES + 1),
                                        rinv + 5 * N_NODES, slot2, N_NODES);
    gather_csr<<<gb2, 256, 0, stream>>>(feat_user_d2, rinv + 6 * N_NODES,
                                        csr + 3 * (size_t)N_EDGES, offs + 3 * (N_NODES + 1),
                                        rinv + 7 * N_NODES, slot3, N_NODES);

    int gb = (N_NODES + 31) / 32;
    // user = slot0@W_i2u_d1 + b1 + slot1@W_i2u_d2 + b2, written to slots 0 and 1
    gemm_pair<<<gb, 256, 0, stream>>>(slot0, W_i2u_d1, b_i2u_d1,
                                      slot1, W_i2u_d2, b_i2u_d2,
                                      slot0, slot1, N_NODES);
    // out_d1 (in place on slot2)
    gemm_pair<<<gb, 256, 0, stream>>>(slot2, W_u2i_d1, b_u2i_d1,
                                      nullptr, nullptr, nullptr,
                                      slot2, nullptr, N_NODES);
    // out_d2 (in place on slot3)
    gemm_pair<<<gb, 256, 0, stream>>>(slot3, W_u2i_d2, b_u2i_d2,
                                      nullptr, nullptr, nullptr,
                                      slot3, nullptr, N_NODES);
}

// Round 3
// 905.442 us; speedup vs baseline: 6.4247x; 1.1580x over previous
//
#include <hip/hip_runtime.h>

#define N_NODES 50000
#define N_EDGES 800000
#define DIM 128
#define NB 49   // ceil(N_NODES / 1024)

struct IdxPtrs8 { const int* p[8]; };
struct SrcDst4  { const int* s[4]; const int* d[4]; };
struct FeatPtrs { const float* f[4]; };
struct GemmArgs { const float* W[4]; const float* b[4]; };

// ---------------------------------------------------------------------------
// 1) degree histogram for all 8 index arrays: blockIdx.y selects the array.
//    4 edges per thread via int4.
// ---------------------------------------------------------------------------
__global__ __launch_bounds__(256) void count_all(IdxPtrs8 idx, int* __restrict__ deg) {
    const int a = blockIdx.y;
    const int* __restrict__ x = idx.p[a];
    int* cnt = deg + (size_t)a * N_NODES;
    int i = blockIdx.x * 256 + threadIdx.x;
    if (i * 4 + 3 < N_EDGES) {        // E divisible by 4, so no tail
        int4 v = ((const int4*)x)[i];
        atomicAdd(&cnt[v.x], 1);
        atomicAdd(&cnt[v.y], 1);
        atomicAdd(&cnt[v.z], 1);
        atomicAdd(&cnt[v.w], 1);
    }
}

// 2) in-place: int count -> float rsqrt(max(count,1))
__global__ __launch_bounds__(256) void deg_to_rinv(int* __restrict__ buf, int n) {
    int i = blockIdx.x * blockDim.x + threadIdx.x;
    if (i < n) {
        int c = buf[i];
        ((float*)buf)[i] = rsqrtf((float)(c < 1 ? 1 : c));
    }
}

// ---------------------------------------------------------------------------
// 3) scan phase A: per-block (1024-node chunk) sums of dst-degree.
//    grid (NB, 4)
// ---------------------------------------------------------------------------
__global__ __launch_bounds__(256) void scan_partial(const int* __restrict__ deg,
                                                    int* __restrict__ part) {
    const int r = blockIdx.y;
    const int* cnt = deg + (size_t)(2 * r + 1) * N_NODES;
    __shared__ int red[256];
    const int tid = threadIdx.x;
    int lo = blockIdx.x * 1024 + tid * 4;
    int s = 0;
#pragma unroll
    for (int j = 0; j < 4; j++) {
        int i = lo + j;
        if (i < N_NODES) s += cnt[i];
    }
    red[tid] = s;
    __syncthreads();
    for (int d = 128; d > 0; d >>= 1) {
        if (tid < d) red[tid] += red[tid + d];
        __syncthreads();
    }
    if (tid == 0) part[r * NB + blockIdx.x] = red[0];
}

// 3b) scan phase B: exclusive scan of the NB partials per relation (in place).
__global__ __launch_bounds__(256) void scan_base(int* __restrict__ part) {
    __shared__ int l[4 * NB];
    const int t = threadIdx.x;
    if (t < 4 * NB) l[t] = part[t];
    __syncthreads();
    if (t < 4) {
        int run = 0;
        for (int b = 0; b < NB; b++) {
            int v = l[t * NB + b];
            l[t * NB + b] = run;
            run += v;
        }
    }
    __syncthreads();
    if (t < 4 * NB) part[t] = l[t];
}

// 3c) scan phase C: local exclusive scan within each 1024-node chunk, add base,
//     write offs + cursor. grid (NB, 4)
__global__ __launch_bounds__(256) void scan_write(const int* __restrict__ deg,
                                                  const int* __restrict__ part,
                                                  int* __restrict__ offs,
                                                  int* __restrict__ cursor) {
    const int r = blockIdx.y;
    const int* cnt = deg + (size_t)(2 * r + 1) * N_NODES;
    int* off = offs + (size_t)r * (N_NODES + 1);
    int* cur = cursor + (size_t)r * N_NODES;
    __shared__ int sums[256];
    const int tid = threadIdx.x;
    int lo = blockIdx.x * 1024 + tid * 4;
    int c[4];
    int s = 0;
#pragma unroll
    for (int j = 0; j < 4; j++) {
        int i = lo + j;
        c[j] = (i < N_NODES) ? cnt[i] : 0;
        s += c[j];
    }
    sums[tid] = s;
    __syncthreads();
    for (int d = 1; d < 256; d <<= 1) {
        int v = (tid >= d) ? sums[tid - d] : 0;
        __syncthreads();
        sums[tid] += v;
        __syncthreads();
    }
    int run = part[r * NB + blockIdx.x] + sums[tid] - s;
#pragma unroll
    for (int j = 0; j < 4; j++) {
        int i = lo + j;
        if (i < N_NODES) {
            off[i] = run;
            cur[i] = run;
            run += c[j];
        }
    }
    if (blockIdx.x == 0 && tid == 0) off[N_NODES] = N_EDGES;
}

// ---------------------------------------------------------------------------
// 4) CSR fill for all 4 relations: blockIdx.y selects relation; int4 reads.
// ---------------------------------------------------------------------------
__global__ __launch_bounds__(256) void fill_all(SrcDst4 sd, int* __restrict__ cursor,
                                                int* __restrict__ csr) {
    const int r = blockIdx.y;
    const int* __restrict__ src = sd.s[r];
    const int* __restrict__ dst = sd.d[r];
    int* cur = cursor + (size_t)r * N_NODES;
    int* out = csr + (size_t)r * N_EDGES;
    int i = blockIdx.x * 256 + threadIdx.x;
    if (i * 4 + 3 < N_EDGES) {
        int4 s = ((const int4*)src)[i];
        int4 d = ((const int4*)dst)[i];
        out[atomicAdd(&cur[d.x], 1)] = s.x;
        out[atomicAdd(&cur[d.y], 1)] = s.y;
        out[atomicAdd(&cur[d.z], 1)] = s.z;
        out[atomicAdd(&cur[d.w], 1)] = s.w;
    }
}

// ---------------------------------------------------------------------------
// 5) gather for all 4 relations: one wave64 per dst node, blockIdx.y = relation.
//    out[d] = rinv_dst[d] * sum_{s in csr row} feat[s] * rinv_src[s]
// ---------------------------------------------------------------------------
__global__ __launch_bounds__(256) void gather_all(
    FeatPtrs feats, const float* __restrict__ rinv,
    const int* __restrict__ csr_all, const int* __restrict__ offs_all,
    float* __restrict__ out_base)
{
    const int r = blockIdx.y;
    const float* __restrict__ feat = feats.f[r];
    const float* __restrict__ rinv_src = rinv + (size_t)(2 * r) * N_NODES;
    const float* __restrict__ rinv_dst = rinv + (size_t)(2 * r + 1) * N_NODES;
    const int* __restrict__ csr = csr_all + (size_t)r * N_EDGES;
    const int* __restrict__ offs = offs_all + (size_t)r * (N_NODES + 1);
    float* out = out_base + (size_t)r * N_NODES * DIM;

    const int node = blockIdx.x * 4 + (threadIdx.x >> 6);
    if (node >= N_NODES) return;
    const int lane = threadIdx.x & 63;
    const int beg = offs[node];
    const int end = offs[node + 1];

    float2 acc = make_float2(0.f, 0.f);
    int i = beg;
    for (; i + 1 < end; i += 2) {
        int s0 = csr[i];
        int s1 = csr[i + 1];
        float sc0 = rinv_src[s0];
        float sc1 = rinv_src[s1];
        float2 v0 = ((const float2*)feat)[(size_t)s0 * 64 + lane];
        float2 v1 = ((const float2*)feat)[(size_t)s1 * 64 + lane];
        acc.x += v0.x * sc0 + v1.x * sc1;
        acc.y += v0.y * sc0 + v1.y * sc1;
    }
    if (i < end) {
        int s0 = csr[i];
        float sc0 = rinv_src[s0];
        float2 v0 = ((const float2*)feat)[(size_t)s0 * 64 + lane];
        acc.x += v0.x * sc0;
        acc.y += v0.y * sc0;
    }
    float rd = rinv_dst[node];
    ((float2*)out)[(size_t)node * 64 + lane] = make_float2(acc.x * rd, acc.y * rd);
}

// ---------------------------------------------------------------------------
// 6) GEMM for all outputs in one launch. blockIdx.y:
//      0: user = slot0@W0 + b0 + slot1@W1 + b1 -> slot0 AND slot1
//      1: out_d1 = slot2@W2 + b2 -> slot2 (in place)
//      2: out_d2 = slot3@W3 + b3 -> slot3 (in place)
//    In-place safe: block stages its own 32 rows in LDS before writing.
// ---------------------------------------------------------------------------
__global__ __launch_bounds__(256) void gemm_all(GemmArgs ga, float* __restrict__ base) {
    __shared__ float Ws[128 * 128];   // 64 KiB
    __shared__ float xs[32 * 128];    // 16 KiB
    const int y = blockIdx.y;
    const int tid = threadIdx.x;
    const int row0 = blockIdx.x * 32;
    const int cg = tid & 31;
    const int rg = tid >> 5;

    float* slot0 = base;
    float* slot1 = base + (size_t)N_NODES * DIM;

    const float* aggA = (y == 0) ? slot0 : base + (size_t)(y + 1) * N_NODES * DIM;
    const float* aggB = (y == 0) ? slot1 : nullptr;
    const float* WA = (y == 0) ? ga.W[0] : ga.W[y + 1];
    const float* bA = (y == 0) ? ga.b[0] : ga.b[y + 1];
    const float* WB = ga.W[1];
    const float* bB = ga.b[1];
    float* outA = (float*)aggA;
    float* outB = (y == 0) ? slot1 : nullptr;

    float acc[4][4];
#pragma unroll
    for (int r = 0; r < 4; r++)
#pragma unroll
        for (int j = 0; j < 4; j++) acc[r][j] = 0.f;

    for (int pass = 0; pass < 2; ++pass) {
        const float* agg = pass ? aggB : aggA;
        const float* W   = pass ? WB   : WA;
        const float* b   = pass ? bB   : bA;
        if (agg == nullptr) break;
        if (pass) __syncthreads();

        // stage W: 4096 float4, 16 per thread
#pragma unroll
        for (int i = 0; i < 16; i++) {
            int f4 = tid + i * 256;
            ((float4*)Ws)[f4] = ((const float4*)W)[f4];
        }
        // stage 32 rows: 1024 float4, 4 per thread
#pragma unroll
        for (int i = 0; i < 4; i++) {
            int f4 = tid + i * 256;
            int row = row0 + (f4 >> 5);
            float4 v = make_float4(0.f, 0.f, 0.f, 0.f);
            if (row < N_NODES) v = ((const float4*)agg)[(size_t)row * 32 + (f4 & 31)];
            ((float4*)xs)[f4] = v;
        }
        __syncthreads();

        float4 bb = ((const float4*)b)[cg];
#pragma unroll
        for (int r = 0; r < 4; r++) {
            acc[r][0] += bb.x; acc[r][1] += bb.y; acc[r][2] += bb.z; acc[r][3] += bb.w;
        }

        const float4* Ws4 = (const float4*)Ws;
        const float4* xs4 = (const float4*)xs;
#pragma unroll 4
        for (int k4 = 0; k4 < 32; k4++) {
            float4 w0 = Ws4[(4 * k4 + 0) * 32 + cg];
            float4 w1 = Ws4[(4 * k4 + 1) * 32 + cg];
            float4 w2 = Ws4[(4 * k4 + 2) * 32 + cg];
            float4 w3 = Ws4[(4 * k4 + 3) * 32 + cg];
#pragma unroll
            for (int rr = 0; rr < 4; rr++) {
                float4 x = xs4[(rg + rr * 8) * 32 + k4];
                acc[rr][0] += x.x * w0.x + x.y * w1.x + x.z * w2.x + x.w * w3.x;
                acc[rr][1] += x.x * w0.y + x.y * w1.y + x.z * w2.y + x.w * w3.y;
                acc[rr][2] += x.x * w0.z + x.y * w1.z + x.z * w2.z + x.w * w3.z;
                acc[rr][3] += x.x * w0.w + x.y * w1.w + x.z * w2.w + x.w * w3.w;
            }
        }
    }

#pragma unroll
    for (int r = 0; r < 4; r++) {
        int row = row0 + rg + r * 8;
        if (row >= N_NODES) continue;
        float4 o = make_float4(acc[r][0], acc[r][1], acc[r][2], acc[r][3]);
        ((float4*)outA)[(size_t)row * 32 + cg] = o;
        if (outB) ((float4*)outB)[(size_t)row * 32 + cg] = o;
    }
}

// ---------------------------------------------------------------------------
extern "C" void kernel_launch(void* const* d_in, const int* in_sizes, int n_in,
                              void* d_out, int out_size, void* d_ws, size_t ws_size,
                              hipStream_t stream) {
    const float* feat_user_d1 = (const float*)d_in[0];
    const float* feat_user_d2 = (const float*)d_in[1];
    const float* feat_d1      = (const float*)d_in[2];
    const float* feat_d2      = (const float*)d_in[3];
    const float* W_i2u_d1 = (const float*)d_in[4];
    const float* b_i2u_d1 = (const float*)d_in[5];
    const float* W_i2u_d2 = (const float*)d_in[6];
    const float* b_i2u_d2 = (const float*)d_in[7];
    const float* W_u2i_d1 = (const float*)d_in[8];
    const float* b_u2i_d1 = (const float*)d_in[9];
    const float* W_u2i_d2 = (const float*)d_in[10];
    const float* b_u2i_d2 = (const float*)d_in[11];
    const int* src_i2u_d1 = (const int*)d_in[12];
    const int* dst_i2u_d1 = (const int*)d_in[13];
    const int* src_i2u_d2 = (const int*)d_in[14];
    const int* dst_i2u_d2 = (const int*)d_in[15];
    const int* src_u2i_d1 = (const int*)d_in[16];
    const int* dst_u2i_d1 = (const int*)d_in[17];
    const int* src_u2i_d2 = (const int*)d_in[18];
    const int* dst_u2i_d2 = (const int*)d_in[19];

    float* out = (float*)d_out;

    // ws layout (ints): deg 8N | offs 4(N+1) | cursor 4N | csr 4E | part 4*NB
    int* deg    = (int*)d_ws;
    const float* rinv = (const float*)d_ws;
    int* offs   = deg + 8 * (size_t)N_NODES;
    int* cursor = offs + 4 * (size_t)(N_NODES + 1);
    int* csr    = cursor + 4 * (size_t)N_NODES;
    int* part   = csr + 4 * (size_t)N_EDGES;

    hipMemsetAsync(deg, 0, 8 * (size_t)N_NODES * sizeof(int), stream);

    // degree slots: [2r]=src, [2r+1]=dst, r in {i2u_d1, i2u_d2, u2i_d1, u2i_d2}
    IdxPtrs8 cidx = {{src_i2u_d1, dst_i2u_d1, src_i2u_d2, dst_i2u_d2,
                      src_u2i_d1, dst_u2i_d1, src_u2i_d2, dst_u2i_d2}};
    count_all<<<dim3((N_EDGES / 4 + 255) / 256, 8), 256, 0, stream>>>(cidx, deg);

    scan_partial<<<dim3(NB, 4), 256, 0, stream>>>(deg, part);
    scan_base<<<1, 256, 0, stream>>>(part);
    scan_write<<<dim3(NB, 4), 256, 0, stream>>>(deg, part, offs, cursor);

    deg_to_rinv<<<(8 * N_NODES + 255) / 256, 256, 0, stream>>>(deg, 8 * N_NODES);

    SrcDst4 sd = {{src_i2u_d1, src_i2u_d2, src_u2i_d1, src_u2i_d2},
                  {dst_i2u_d1, dst_i2u_d2, dst_u2i_d1, dst_u2i_d2}};
    fill_all<<<dim3((N_EDGES / 4 + 255) / 256, 4), 256, 0, stream>>>(sd, cursor, csr);

    FeatPtrs fp = {{feat_d1, feat_d2, feat_user_d1, feat_user_d2}};
    gather_all<<<dim3((N_NODES + 3) / 4, 4), 256, 0, stream>>>(fp, rinv, csr, offs, out);

    GemmArgs ga = {{W_i2u_d1, W_i2u_d2, W_u2i_d1, W_u2i_d2},
                   {b_i2u_d1, b_i2u_d2, b_u2i_d1, b_u2i_d2}};
    gemm_all<<<dim3((N_NODES + 31) / 32, 3), 256, 0, stream>>>(ga, out);
}

// Round 4
// 802.581 us; speedup vs baseline: 7.2481x; 1.1282x over previous
//
#include <hip/hip_runtime.h>

#define N_NODES 50000
#define N_EDGES 800000
#define DIM 128
#define NB 49   // ceil(N_NODES / 1024)

struct IdxPtrs8 { const int* p[8]; };
struct SrcDst4  { const int* s[4]; const int* d[4]; };
struct FeatPtrs { const float* f[4]; };
struct GemmArgs { const float* W[4]; const float* b[4]; };

// ---------------------------------------------------------------------------
// 1) degree histogram for all 8 index arrays: blockIdx.y selects the array.
// ---------------------------------------------------------------------------
__global__ __launch_bounds__(256) void count_all(IdxPtrs8 idx, int* __restrict__ deg) {
    const int a = blockIdx.y;
    const int* __restrict__ x = idx.p[a];
    int* cnt = deg + (size_t)a * N_NODES;
    int i = blockIdx.x * 256 + threadIdx.x;
    if (i * 4 + 3 < N_EDGES) {        // E divisible by 4
        int4 v = ((const int4*)x)[i];
        atomicAdd(&cnt[v.x], 1);
        atomicAdd(&cnt[v.y], 1);
        atomicAdd(&cnt[v.z], 1);
        atomicAdd(&cnt[v.w], 1);
    }
}

// 2) in-place: int count -> float rsqrt(max(count,1))
__global__ __launch_bounds__(256) void deg_to_rinv(int* __restrict__ buf, int n) {
    int i = blockIdx.x * blockDim.x + threadIdx.x;
    if (i < n) {
        int c = buf[i];
        ((float*)buf)[i] = rsqrtf((float)(c < 1 ? 1 : c));
    }
}

// ---------------------------------------------------------------------------
// 3) multi-block scan of dst-degrees -> CSR offsets + cursors
// ---------------------------------------------------------------------------
__global__ __launch_bounds__(256) void scan_partial(const int* __restrict__ deg,
                                                    int* __restrict__ part) {
    const int r = blockIdx.y;
    const int* cnt = deg + (size_t)(2 * r + 1) * N_NODES;
    __shared__ int red[256];
    const int tid = threadIdx.x;
    int lo = blockIdx.x * 1024 + tid * 4;
    int s = 0;
#pragma unroll
    for (int j = 0; j < 4; j++) {
        int i = lo + j;
        if (i < N_NODES) s += cnt[i];
    }
    red[tid] = s;
    __syncthreads();
    for (int d = 128; d > 0; d >>= 1) {
        if (tid < d) red[tid] += red[tid + d];
        __syncthreads();
    }
    if (tid == 0) part[r * NB + blockIdx.x] = red[0];
}

__global__ __launch_bounds__(256) void scan_base(int* __restrict__ part) {
    __shared__ int l[4 * NB];
    const int t = threadIdx.x;
    if (t < 4 * NB) l[t] = part[t];
    __syncthreads();
    if (t < 4) {
        int run = 0;
        for (int b = 0; b < NB; b++) {
            int v = l[t * NB + b];
            l[t * NB + b] = run;
            run += v;
        }
    }
    __syncthreads();
    if (t < 4 * NB) part[t] = l[t];
}

__global__ __launch_bounds__(256) void scan_write(const int* __restrict__ deg,
                                                  const int* __restrict__ part,
                                                  int* __restrict__ offs,
                                                  int* __restrict__ cursor) {
    const int r = blockIdx.y;
    const int* cnt = deg + (size_t)(2 * r + 1) * N_NODES;
    int* off = offs + (size_t)r * (N_NODES + 1);
    int* cur = cursor + (size_t)r * N_NODES;
    __shared__ int sums[256];
    const int tid = threadIdx.x;
    int lo = blockIdx.x * 1024 + tid * 4;
    int c[4];
    int s = 0;
#pragma unroll
    for (int j = 0; j < 4; j++) {
        int i = lo + j;
        c[j] = (i < N_NODES) ? cnt[i] : 0;
        s += c[j];
    }
    sums[tid] = s;
    __syncthreads();
    for (int d = 1; d < 256; d <<= 1) {
        int v = (tid >= d) ? sums[tid - d] : 0;
        __syncthreads();
        sums[tid] += v;
        __syncthreads();
    }
    int run = part[r * NB + blockIdx.x] + sums[tid] - s;
#pragma unroll
    for (int j = 0; j < 4; j++) {
        int i = lo + j;
        if (i < N_NODES) {
            off[i] = run;
            cur[i] = run;
            run += c[j];
        }
    }
    if (blockIdx.x == 0 && tid == 0) off[N_NODES] = N_EDGES;
}

// ---------------------------------------------------------------------------
// 4) CSR fill for all 4 relations
// ---------------------------------------------------------------------------
__global__ __launch_bounds__(256) void fill_all(SrcDst4 sd, int* __restrict__ cursor,
                                                int* __restrict__ csr) {
    const int r = blockIdx.y;
    const int* __restrict__ src = sd.s[r];
    const int* __restrict__ dst = sd.d[r];
    int* cur = cursor + (size_t)r * N_NODES;
    int* out = csr + (size_t)r * N_EDGES;
    int i = blockIdx.x * 256 + threadIdx.x;
    if (i * 4 + 3 < N_EDGES) {
        int4 s = ((const int4*)src)[i];
        int4 d = ((const int4*)dst)[i];
        out[atomicAdd(&cur[d.x], 1)] = s.x;
        out[atomicAdd(&cur[d.y], 1)] = s.y;
        out[atomicAdd(&cur[d.z], 1)] = s.z;
        out[atomicAdd(&cur[d.w], 1)] = s.w;
    }
}

// ---------------------------------------------------------------------------
// 4b) fp32 -> bf16 feature conversion (RNE). Table y, 8 elems/thread.
//     Packing: uint j holds elems {2j (lo16), 2j+1 (hi16)}.
// ---------------------------------------------------------------------------
__device__ inline unsigned f2bf(float x) {
    unsigned u = __float_as_uint(x);
    return (u + 0x7fffu + ((u >> 16) & 1u)) >> 16;
}

__global__ __launch_bounds__(256) void to_bf16(FeatPtrs fp, unsigned short* __restrict__ bf) {
    const int y = blockIdx.y;
    const float* __restrict__ f = fp.f[y];
    uint4* __restrict__ o = (uint4*)(bf + (size_t)y * N_NODES * DIM);
    int i = blockIdx.x * 256 + threadIdx.x;          // 8 elems per thread
    if (i * 8 + 7 < N_NODES * DIM) {
        float4 v0 = ((const float4*)f)[i * 2];
        float4 v1 = ((const float4*)f)[i * 2 + 1];
        uint4 p;
        p.x = (f2bf(v0.y) << 16) | f2bf(v0.x);
        p.y = (f2bf(v0.w) << 16) | f2bf(v0.z);
        p.z = (f2bf(v1.y) << 16) | f2bf(v1.x);
        p.w = (f2bf(v1.w) << 16) | f2bf(v1.z);
        o[i] = p;
    }
}

// ---------------------------------------------------------------------------
// 5) gather, bf16 features: one wave64 per dst node; 32 lanes per edge row
//    (8 B/lane), two edges per wave in parallel (sub = lane>>5), 2-deep unroll.
// ---------------------------------------------------------------------------
__global__ __launch_bounds__(256) void gather_bf16(
    const unsigned short* __restrict__ bf, const float* __restrict__ rinv,
    const int* __restrict__ csr_all, const int* __restrict__ offs_all,
    float* __restrict__ out_base)
{
    const int r = blockIdx.y;
    const unsigned short* __restrict__ feat = bf + (size_t)r * N_NODES * DIM;
    const float* __restrict__ rinv_src = rinv + (size_t)(2 * r) * N_NODES;
    const float* __restrict__ rinv_dst = rinv + (size_t)(2 * r + 1) * N_NODES;
    const int* __restrict__ csr = csr_all + (size_t)r * N_EDGES;
    const int* __restrict__ offs = offs_all + (size_t)r * (N_NODES + 1);
    float* out = out_base + (size_t)r * N_NODES * DIM;

    const int node = blockIdx.x * 4 + (threadIdx.x >> 6);
    if (node >= N_NODES) return;
    const int lane = threadIdx.x & 63;
    const int sub = lane >> 5;     // which edge of the pair
    const int l = lane & 31;       // covers cols [4l, 4l+4)
    const int beg = offs[node];
    const int end = offs[node + 1];
    const uint2* __restrict__ feat2 = (const uint2*)feat;

    float4 acc = make_float4(0.f, 0.f, 0.f, 0.f);
    int i = beg + sub;
    for (; i + 2 < end; i += 4) {
        int s0 = csr[i];
        int s1 = csr[i + 2];
        float sc0 = rinv_src[s0];
        float sc1 = rinv_src[s1];
        uint2 q0 = feat2[(size_t)s0 * 32 + l];
        uint2 q1 = feat2[(size_t)s1 * 32 + l];
        acc.x = fmaf(__uint_as_float(q0.x << 16),          sc0, acc.x);
        acc.y = fmaf(__uint_as_float(q0.x & 0xffff0000u),  sc0, acc.y);
        acc.z = fmaf(__uint_as_float(q0.y << 16),          sc0, acc.z);
        acc.w = fmaf(__uint_as_float(q0.y & 0xffff0000u),  sc0, acc.w);
        acc.x = fmaf(__uint_as_float(q1.x << 16),          sc1, acc.x);
        acc.y = fmaf(__uint_as_float(q1.x & 0xffff0000u),  sc1, acc.y);
        acc.z = fmaf(__uint_as_float(q1.y << 16),          sc1, acc.z);
        acc.w = fmaf(__uint_as_float(q1.y & 0xffff0000u),  sc1, acc.w);
    }
    if (i < end) {
        int s0 = csr[i];
        float sc0 = rinv_src[s0];
        uint2 q0 = feat2[(size_t)s0 * 32 + l];
        acc.x = fmaf(__uint_as_float(q0.x << 16),          sc0, acc.x);
        acc.y = fmaf(__uint_as_float(q0.x & 0xffff0000u),  sc0, acc.y);
        acc.z = fmaf(__uint_as_float(q0.y << 16),          sc0, acc.z);
        acc.w = fmaf(__uint_as_float(q0.y & 0xffff0000u),  sc0, acc.w);
    }
    // combine the two half-wave partials
    acc.x += __shfl_xor(acc.x, 32);
    acc.y += __shfl_xor(acc.y, 32);
    acc.z += __shfl_xor(acc.z, 32);
    acc.w += __shfl_xor(acc.w, 32);
    if (sub == 0) {
        float rd = rinv_dst[node];
        ((float4*)out)[(size_t)node * 32 + l] =
            make_float4(acc.x * rd, acc.y * rd, acc.z * rd, acc.w * rd);
    }
}

// 5b) fp32 fallback gather (same structure, float4 rows)
__global__ __launch_bounds__(256) void gather_f32(
    FeatPtrs feats, const float* __restrict__ rinv,
    const int* __restrict__ csr_all, const int* __restrict__ offs_all,
    float* __restrict__ out_base)
{
    const int r = blockIdx.y;
    const float* __restrict__ feat = feats.f[r];
    const float* __restrict__ rinv_src = rinv + (size_t)(2 * r) * N_NODES;
    const float* __restrict__ rinv_dst = rinv + (size_t)(2 * r + 1) * N_NODES;
    const int* __restrict__ csr = csr_all + (size_t)r * N_EDGES;
    const int* __restrict__ offs = offs_all + (size_t)r * (N_NODES + 1);
    float* out = out_base + (size_t)r * N_NODES * DIM;

    const int node = blockIdx.x * 4 + (threadIdx.x >> 6);
    if (node >= N_NODES) return;
    const int lane = threadIdx.x & 63;
    const int sub = lane >> 5;
    const int l = lane & 31;
    const int beg = offs[node];
    const int end = offs[node + 1];
    const float4* __restrict__ feat4 = (const float4*)feat;

    float4 acc = make_float4(0.f, 0.f, 0.f, 0.f);
    int i = beg + sub;
    for (; i + 2 < end; i += 4) {
        int s0 = csr[i];
        int s1 = csr[i + 2];
        float sc0 = rinv_src[s0];
        float sc1 = rinv_src[s1];
        float4 v0 = feat4[(size_t)s0 * 32 + l];
        float4 v1 = feat4[(size_t)s1 * 32 + l];
        acc.x = fmaf(v0.x, sc0, acc.x); acc.y = fmaf(v0.y, sc0, acc.y);
        acc.z = fmaf(v0.z, sc0, acc.z); acc.w = fmaf(v0.w, sc0, acc.w);
        acc.x = fmaf(v1.x, sc1, acc.x); acc.y = fmaf(v1.y, sc1, acc.y);
        acc.z = fmaf(v1.z, sc1, acc.z); acc.w = fmaf(v1.w, sc1, acc.w);
    }
    if (i < end) {
        int s0 = csr[i];
        float sc0 = rinv_src[s0];
        float4 v0 = feat4[(size_t)s0 * 32 + l];
        acc.x = fmaf(v0.x, sc0, acc.x); acc.y = fmaf(v0.y, sc0, acc.y);
        acc.z = fmaf(v0.z, sc0, acc.z); acc.w = fmaf(v0.w, sc0, acc.w);
    }
    acc.x += __shfl_xor(acc.x, 32);
    acc.y += __shfl_xor(acc.y, 32);
    acc.z += __shfl_xor(acc.z, 32);
    acc.w += __shfl_xor(acc.w, 32);
    if (sub == 0) {
        float rd = rinv_dst[node];
        ((float4*)out)[(size_t)node * 32 + l] =
            make_float4(acc.x * rd, acc.y * rd, acc.z * rd, acc.w * rd);
    }
}

// ---------------------------------------------------------------------------
// 6) GEMM for all outputs in one launch. blockIdx.y:
//      0: user = slot0@W0 + b0 + slot1@W1 + b1 -> slot0 AND slot1
//      1: out_d1 = slot2@W2 + b2 -> slot2 (in place)
//      2: out_d2 = slot3@W3 + b3 -> slot3 (in place)
// ---------------------------------------------------------------------------
__global__ __launch_bounds__(256) void gemm_all(GemmArgs ga, float* __restrict__ base) {
    __shared__ float Ws[128 * 128];
    __shared__ float xs[32 * 128];
    const int y = blockIdx.y;
    const int tid = threadIdx.x;
    const int row0 = blockIdx.x * 32;
    const int cg = tid & 31;
    const int rg = tid >> 5;

    float* slot0 = base;
    float* slot1 = base + (size_t)N_NODES * DIM;

    const float* aggA = (y == 0) ? slot0 : base + (size_t)(y + 1) * N_NODES * DIM;
    const float* aggB = (y == 0) ? slot1 : nullptr;
    const float* WA = (y == 0) ? ga.W[0] : ga.W[y + 1];
    const float* bA = (y == 0) ? ga.b[0] : ga.b[y + 1];
    const float* WB = ga.W[1];
    const float* bB = ga.b[1];
    float* outA = (float*)aggA;
    float* outB = (y == 0) ? slot1 : nullptr;

    float acc[4][4];
#pragma unroll
    for (int r = 0; r < 4; r++)
#pragma unroll
        for (int j = 0; j < 4; j++) acc[r][j] = 0.f;

    for (int pass = 0; pass < 2; ++pass) {
        const float* agg = pass ? aggB : aggA;
        const float* W   = pass ? WB   : WA;
        const float* b   = pass ? bB   : bA;
        if (agg == nullptr) break;
        if (pass) __syncthreads();

#pragma unroll
        for (int i = 0; i < 16; i++) {
            int f4 = tid + i * 256;
            ((float4*)Ws)[f4] = ((const float4*)W)[f4];
        }
#pragma unroll
        for (int i = 0; i < 4; i++) {
            int f4 = tid + i * 256;
            int row = row0 + (f4 >> 5);
            float4 v = make_float4(0.f, 0.f, 0.f, 0.f);
            if (row < N_NODES) v = ((const float4*)agg)[(size_t)row * 32 + (f4 & 31)];
            ((float4*)xs)[f4] = v;
        }
        __syncthreads();

        float4 bb = ((const float4*)b)[cg];
#pragma unroll
        for (int r = 0; r < 4; r++) {
            acc[r][0] += bb.x; acc[r][1] += bb.y; acc[r][2] += bb.z; acc[r][3] += bb.w;
        }

        const float4* Ws4 = (const float4*)Ws;
        const float4* xs4 = (const float4*)xs;
#pragma unroll 4
        for (int k4 = 0; k4 < 32; k4++) {
            float4 w0 = Ws4[(4 * k4 + 0) * 32 + cg];
            float4 w1 = Ws4[(4 * k4 + 1) * 32 + cg];
            float4 w2 = Ws4[(4 * k4 + 2) * 32 + cg];
            float4 w3 = Ws4[(4 * k4 + 3) * 32 + cg];
#pragma unroll
            for (int rr = 0; rr < 4; rr++) {
                float4 x = xs4[(rg + rr * 8) * 32 + k4];
                acc[rr][0] += x.x * w0.x + x.y * w1.x + x.z * w2.x + x.w * w3.x;
                acc[rr][1] += x.x * w0.y + x.y * w1.y + x.z * w2.y + x.w * w3.y;
                acc[rr][2] += x.x * w0.z + x.y * w1.z + x.z * w2.z + x.w * w3.z;
                acc[rr][3] += x.x * w0.w + x.y * w1.w + x.z * w2.w + x.w * w3.w;
            }
        }
    }

#pragma unroll
    for (int r = 0; r < 4; r++) {
        int row = row0 + rg + r * 8;
        if (row >= N_NODES) continue;
        float4 o = make_float4(acc[r][0], acc[r][1], acc[r][2], acc[r][3]);
        ((float4*)outA)[(size_t)row * 32 + cg] = o;
        if (outB) ((float4*)outB)[(size_t)row * 32 + cg] = o;
    }
}

// ---------------------------------------------------------------------------
extern "C" void kernel_launch(void* const* d_in, const int* in_sizes, int n_in,
                              void* d_out, int out_size, void* d_ws, size_t ws_size,
                              hipStream_t stream) {
    const float* feat_user_d1 = (const float*)d_in[0];
    const float* feat_user_d2 = (const float*)d_in[1];
    const float* feat_d1      = (const float*)d_in[2];
    const float* feat_d2      = (const float*)d_in[3];
    const float* W_i2u_d1 = (const float*)d_in[4];
    const float* b_i2u_d1 = (const float*)d_in[5];
    const float* W_i2u_d2 = (const float*)d_in[6];
    const float* b_i2u_d2 = (const float*)d_in[7];
    const float* W_u2i_d1 = (const float*)d_in[8];
    const float* b_u2i_d1 = (const float*)d_in[9];
    const float* W_u2i_d2 = (const float*)d_in[10];
    const float* b_u2i_d2 = (const float*)d_in[11];
    const int* src_i2u_d1 = (const int*)d_in[12];
    const int* dst_i2u_d1 = (const int*)d_in[13];
    const int* src_i2u_d2 = (const int*)d_in[14];
    const int* dst_i2u_d2 = (const int*)d_in[15];
    const int* src_u2i_d1 = (const int*)d_in[16];
    const int* dst_u2i_d1 = (const int*)d_in[17];
    const int* src_u2i_d2 = (const int*)d_in[18];
    const int* dst_u2i_d2 = (const int*)d_in[19];

    float* out = (float*)d_out;

    // ws (ints): deg 8N | offs 4(N+1) | cursor 4N | csr 4E | part(+pad) 256 | bf16 feats
    int* deg    = (int*)d_ws;
    const float* rinv = (const float*)d_ws;
    int* offs   = deg + 8 * (size_t)N_NODES;
    int* cursor = offs + 4 * (size_t)(N_NODES + 1);
    int* csr    = cursor + 4 * (size_t)N_NODES;
    int* part   = csr + 4 * (size_t)N_EDGES;
    unsigned short* bf = (unsigned short*)(part + 256);
    size_t need_bf = ((char*)(bf + 4 * (size_t)N_NODES * DIM)) - (char*)d_ws;
    const bool use_bf16 = (ws_size >= need_bf);

    hipMemsetAsync(deg, 0, 8 * (size_t)N_NODES * sizeof(int), stream);

    IdxPtrs8 cidx = {{src_i2u_d1, dst_i2u_d1, src_i2u_d2, dst_i2u_d2,
                      src_u2i_d1, dst_u2i_d1, src_u2i_d2, dst_u2i_d2}};
    count_all<<<dim3((N_EDGES / 4 + 255) / 256, 8), 256, 0, stream>>>(cidx, deg);

    scan_partial<<<dim3(NB, 4), 256, 0, stream>>>(deg, part);
    scan_base<<<1, 256, 0, stream>>>(part);
    scan_write<<<dim3(NB, 4), 256, 0, stream>>>(deg, part, offs, cursor);

    deg_to_rinv<<<(8 * N_NODES + 255) / 256, 256, 0, stream>>>(deg, 8 * N_NODES);

    SrcDst4 sd = {{src_i2u_d1, src_i2u_d2, src_u2i_d1, src_u2i_d2},
                  {dst_i2u_d1, dst_i2u_d2, dst_u2i_d1, dst_u2i_d2}};
    fill_all<<<dim3((N_EDGES / 4 + 255) / 256, 4), 256, 0, stream>>>(sd, cursor, csr);

    FeatPtrs fp = {{feat_d1, feat_d2, feat_user_d1, feat_user_d2}};
    if (use_bf16) {
        to_bf16<<<dim3((N_NODES * DIM / 8 + 255) / 256, 4), 256, 0, stream>>>(fp, bf);
        gather_bf16<<<dim3((N_NODES + 3) / 4, 4), 256, 0, stream>>>(bf, rinv, csr, offs, out);
    } else {
        gather_f32<<<dim3((N_NODES + 3) / 4, 4), 256, 0, stream>>>(fp, rinv, csr, offs, out);
    }

    GemmArgs ga = {{W_i2u_d1, W_i2u_d2, W_u2i_d1, W_u2i_d2},
                   {b_i2u_d1, b_i2u_d2, b_u2i_d1, b_u2i_d2}};
    gemm_all<<<dim3((N_NODES + 31) / 32, 3), 256, 0, stream>>>(ga, out);
}